// Round 7
// baseline (187.283 us; speedup 1.0000x reference)
//
#include <hip/hip_runtime.h>
#include <hip/hip_bf16.h>
#include <math.h>

#define BATCH 2
#define SEQ   2048
#define DMODEL 1024
#define NHEADS 16
#define HDIM  64
#define MROWS (BATCH*SEQ)   // 4096
#define QSCALE 0.1803368801111204f   // 0.125 * log2(e); attention uses exp2

typedef __attribute__((ext_vector_type(8))) short bfr8;   // 8 bf16 (4 VGPRs)
typedef __attribute__((ext_vector_type(4))) float f32x4;  // MFMA C/D

__device__ inline unsigned short f2bf(float f) {
    union { float f; unsigned u; } v; v.f = f;
    unsigned r = v.u + 0x7FFFu + ((v.u >> 16) & 1u);   // RNE
    return (unsigned short)(r >> 16);
}

__device__ inline unsigned pack2bf(float a, float b) {   // low=a, high=b
    union { __hip_bfloat162 h; unsigned u; } cv;
    cv.h = __float22bfloat162_rn(float2{a, b});
    return cv.u;
}

__device__ inline void gload16(const unsigned short* g, unsigned short* l) {
    __builtin_amdgcn_global_load_lds((const __attribute__((address_space(1))) void*)g,
        (__attribute__((address_space(3))) void*)l, 16, 0, 0);
}

// ---------------- casts fp32 -> bf16 ----------------
__global__ __launch_bounds__(256) void cast_bf16(const float* __restrict__ in,
                                                 unsigned short* __restrict__ out, int n) {
    int i = (blockIdx.x * 256 + threadIdx.x) * 4;
    const int stride = gridDim.x * 256 * 4;
    for (; i < n; i += stride) {
        float4 v = *(const float4*)(in + i);
        ushort4 o;
        o.x = f2bf(v.x); o.y = f2bf(v.y); o.z = f2bf(v.z); o.w = f2bf(v.w);
        *(ushort4*)(out + i) = o;
    }
}

// 4 weight matrices (each 2^20 elems) -> contiguous dst
__global__ __launch_bounds__(256) void cast4_bf16(
    const float* __restrict__ a, const float* __restrict__ b,
    const float* __restrict__ c, const float* __restrict__ d,
    unsigned short* __restrict__ out) {
    const int NW = 1 << 20;
    int i = (blockIdx.x * 256 + threadIdx.x) * 4;
    const int stride = gridDim.x * 256 * 4;
    for (; i < 4 * NW; i += stride) {
        const int seg = i >> 20;
        const float* src = seg == 0 ? a : seg == 1 ? b : seg == 2 ? c : d;
        float4 v = *(const float4*)(src + (i & (NW - 1)));
        ushort4 o;
        o.x = f2bf(v.x); o.y = f2bf(v.y); o.z = f2bf(v.z); o.w = f2bf(v.w);
        *(ushort4*)(out + i) = o;
    }
}

// ---------------- bf16 MFMA GEMM: Y = A @ W^T + bias ----------------
// Tile BM x 128, BK=32, 4 waves. 3-buffer LDS pipeline, 2-deep prefetch,
// counted vmcnt (never 0 in steady state) fused with s_barrier.
// MODE 0: N=3072 fused QKV; proj=col/1024; Q scaled by QSCALE; Q,K->[B,H,T,64], V->[B,H,64,T]
// MODE 2: N=1024, fp32 linear output [4096,1024], bias b0
template<int BM, int MODE>
__global__ __launch_bounds__(256) void gemm_bf16(
    const unsigned short* __restrict__ A, const unsigned short* __restrict__ W,
    const float* __restrict__ b0, const float* __restrict__ b1,
    const float* __restrict__ b2, void* __restrict__ Y)
{
    __shared__ __align__(16) unsigned short As[3][4][BM][8];
    __shared__ __align__(16) unsigned short Bs[3][4][128][8];

    constexpr int NT  = 32;            // K / 32
    constexpr int NLD = BM / 64 + 2;   // gload_lds instrs per thread per stage

    const int tid = threadIdx.x;
    const int l = tid & 63, w = tid >> 6;
    const int wr = w >> 1, wc = w & 1;
    const int m0 = blockIdx.y * BM, n0 = blockIdx.x * 128;
    const int r15 = l & 15, g = l >> 4;
    constexpr int MR = BM / 32;

    f32x4 acc[MR][4] = {};

    auto stage = [&](int buf, int t) {
        const int k0 = t * 32;
        #pragma unroll
        for (int s = 0; s < BM / 64; ++s) {
            int idx = s * 256 + tid;
            int row = idx % BM, kg = idx / BM;
            gload16(A + (size_t)(m0 + row) * 1024 + k0 + kg * 8, &As[buf][kg][row][0]);
        }
        #pragma unroll
        for (int s = 0; s < 2; ++s) {
            int idx = s * 256 + tid;
            int row = idx & 127, kg = idx >> 7;
            gload16(W + (size_t)(n0 + row) * 1024 + k0 + kg * 8, &Bs[buf][kg][row][0]);
        }
    };

    stage(0, 0);
    stage(1, 1);

    for (int t = 0; t < NT; ++t) {
        // tile t landed (newest stage may remain in flight), then block-wide sync
        if (t < NT - 1)
            asm volatile("s_waitcnt vmcnt(%0)\ns_barrier" :: "n"(NLD) : "memory");
        else
            asm volatile("s_waitcnt vmcnt(0)\ns_barrier" ::: "memory");
        if (t + 2 < NT) stage((t + 2) % 3, t + 2);

        const int buf = t % 3;
        bfr8 a[MR], b[4];
        #pragma unroll
        for (int m = 0; m < MR; ++m)
            a[m] = *(const bfr8*)&As[buf][g][wr * (BM / 2) + m * 16 + r15][0];
        #pragma unroll
        for (int n = 0; n < 4; ++n)
            b[n] = *(const bfr8*)&Bs[buf][g][wc * 64 + n * 16 + r15][0];
        #pragma unroll
        for (int m = 0; m < MR; ++m)
            #pragma unroll
            for (int n = 0; n < 4; ++n)
                acc[m][n] = __builtin_amdgcn_mfma_f32_16x16x32_bf16(a[m], b[n], acc[m][n], 0, 0, 0);
    }

    const size_t NX = (size_t)MROWS * DMODEL;
    #pragma unroll
    for (int m = 0; m < MR; ++m) {
        const int rowb = m0 + wr * (BM / 2) + m * 16 + g * 4;
        #pragma unroll
        for (int n = 0; n < 4; ++n) {
            const int col = n0 + wc * 64 + n * 16 + r15;
            const int proj = col >> 10, within = col & 1023;
            const float bc = (MODE == 2) ? b0[col]
                           : (proj == 0 ? b0[within] : proj == 1 ? b1[within] : b2[within]);
            #pragma unroll
            for (int i = 0; i < 4; ++i) {
                float v = acc[m][n][i] + bc;
                const int rr = rowb + i;
                if (MODE == 2) {
                    ((float*)Y)[(size_t)rr * 1024 + col] = v;
                } else {
                    if (proj == 0) v *= QSCALE;
                    const int bb = rr >> 11, tt = rr & 2047;
                    const int hh = within >> 6, dd = within & 63;
                    unsigned short* dst = (unsigned short*)Y + (size_t)proj * NX;
                    size_t idx;
                    if (proj < 2)
                        idx = (((size_t)bb * NHEADS + hh) * SEQ + tt) * HDIM + dd;
                    else
                        idx = (((size_t)bb * NHEADS + hh) * HDIM + dd) * SEQ + tt;
                    dst[idx] = f2bf(v);
                }
            }
        }
    }
}

// ---------------- MFMA flash attention (causal, fully lane-local softmax) ----------------
// Q,K: [B,H,T,64] bf16 (Q pre-scaled by 0.125*log2e); VT: [B,H,64,T]; O: [B,T,1024] bf16.
// Block: 4 waves x 16 q-rows = 64 q. S^T = mfma(K, Q^T): C col = q = r15.
// PV transposed: o' = mfma(V^T-frag, P-frag). Softmax fully lane-local; defer-max THR=8.
// KV tile 64, 3-buffer LDS pipeline with counted vmcnt + raw s_barrier.
__global__ __launch_bounds__(256, 2) void attn_mfma(
    const unsigned short* __restrict__ Q, const unsigned short* __restrict__ K,
    const unsigned short* __restrict__ VT, unsigned short* __restrict__ O)
{
    __shared__ __align__(16) unsigned short Ks[3][64][64];   // [kv][d] granule-swizzled (24K)
    __shared__ __align__(16) unsigned short Vs[3][64][64];   // [d][kv] granule-swizzled (24K)
    __shared__ __align__(16) unsigned short Ps[4][8][16][8]; // [wave][kg][q][e]  (8K)

    const int tid = threadIdx.x;
    const int l = tid & 63, w = tid >> 6;
    const int r15 = l & 15, g2 = l >> 4;          // g2 = 0..3
    const int qt = (blockIdx.x + blockIdx.y) & 31;   // decorrelate length from CU
    const int q0 = SEQ - 64 - qt * 64;
    const int q  = q0 + w * 16 + r15;             // this lane's q column
    const int bh = blockIdx.y;

    const unsigned short* Qb = Q + (size_t)bh * SEQ * HDIM;
    const unsigned short* Kb = K + (size_t)bh * SEQ * HDIM;
    const unsigned short* Vb = VT + (size_t)bh * HDIM * SEQ;

    // Q B-frag: lane holds Q[q][ks*32 + g2*8 .. +7]  (issued before stages: oldest in FIFO)
    bfr8 qf[2];
    qf[0] = *(const bfr8*)(Qb + (size_t)q * HDIM + g2 * 8);
    qf[1] = *(const bfr8*)(Qb + (size_t)q * HDIM + 32 + g2 * 8);

    auto stage = [&](int buf, int kv0) {
        #pragma unroll
        for (int s = 0; s < 2; ++s) {
            int idx = s * 256 + tid;               // 512 granules each of K, V
            int row = idx >> 3, gs = idx & 7;
            gload16(Kb + (size_t)(kv0 + row) * HDIM + ((gs ^ (row & 7)) * 8), &Ks[buf][row][gs * 8]);
            gload16(Vb + (size_t)row * SEQ + kv0 + ((gs ^ (row & 7)) * 8), &Vs[buf][row][gs * 8]);
        }
    };

    f32x4 o[4] = {};                 // o[ch][i]: d = ch*16 + g2*4 + i, col q
    float m = -INFINITY, rden = 0.f;

    const int ntiles = q0 / 64 + 1;
    stage(0, 0);
    if (ntiles > 1) stage(1, 64);

    for (int kt = 0; kt < ntiles; ++kt) {
        const int kv0 = kt * 64, buf = kt % 3;
        // tile kt landed; newest stage stays in flight (4 loads) except last iter
        if (kt < ntiles - 1)
            asm volatile("s_waitcnt vmcnt(4)\ns_barrier" ::: "memory");
        else
            asm volatile("s_waitcnt vmcnt(0)\ns_barrier" ::: "memory");
        if (kt + 2 < ntiles) stage((kt + 2) % 3, kv0 + 128);

        // ---- S^T = K @ Q^T : s[c][i], kv = c*16 + g2*4 + i, q = col r15 ----
        f32x4 s[4];
        #pragma unroll
        for (int c = 0; c < 4; ++c) {
            const int rk = c * 16 + r15;
            const bfr8 kf0 = *(const bfr8*)&Ks[buf][rk][(g2 ^ (r15 & 7)) * 8];
            const bfr8 kf1 = *(const bfr8*)&Ks[buf][rk][((4 + g2) ^ (r15 & 7)) * 8];
            f32x4 z = {0.f, 0.f, 0.f, 0.f};
            z = __builtin_amdgcn_mfma_f32_16x16x32_bf16(kf0, qf[0], z, 0, 0, 0);
            s[c] = __builtin_amdgcn_mfma_f32_16x16x32_bf16(kf1, qf[1], z, 0, 0, 0);
        }

        if (kt == ntiles - 1) {      // causal mask: only the diagonal tile
            #pragma unroll
            for (int c = 0; c < 4; ++c)
                #pragma unroll
                for (int i = 0; i < 4; ++i)
                    if (kv0 + c * 16 + g2 * 4 + i > q) s[c][i] = -INFINITY;
        }

        // ---- lane-local online softmax with defer-max ----
        float tm = s[0][0];
        #pragma unroll
        for (int c = 0; c < 4; ++c)
            #pragma unroll
            for (int i = 0; i < 4; ++i) tm = fmaxf(tm, s[c][i]);
        tm = fmaxf(tm, __shfl_xor(tm, 16));
        tm = fmaxf(tm, __shfl_xor(tm, 32));
        if (__any(tm > m + 8.f)) {            // rescale (always taken on first tile)
            const float mn = fmaxf(m, tm);
            const float scl = exp2f(m - mn);  // 0 on first tile
            m = mn;
            rden *= scl;
            #pragma unroll
            for (int ch = 0; ch < 4; ++ch)
                #pragma unroll
                for (int i = 0; i < 4; ++i) o[ch][i] *= scl;
        }
        float ls = 0.f;
        #pragma unroll
        for (int c = 0; c < 4; ++c)
            #pragma unroll
            for (int i = 0; i < 4; ++i) {
                const float p = exp2f(s[c][i] - m);
                s[c][i] = p;
                ls += p;
            }
        ls += __shfl_xor(ls, 16);
        ls += __shfl_xor(ls, 32);
        rden += ls;

        // ---- P -> LDS in B-frag layout: Ps[kg][q][e] = P[kv=kg*8+e][q] ----
        {
            const int eb = (g2 & 1) * 4;
            #pragma unroll
            for (int c = 0; c < 4; ++c) {
                const int kg = c * 2 + (g2 >> 1);
                *(unsigned*)&Ps[w][kg][r15][eb]     = pack2bf(s[c][0], s[c][1]);
                *(unsigned*)&Ps[w][kg][r15][eb + 2] = pack2bf(s[c][2], s[c][3]);
            }
        }
        // wave-private buffer: within-wave lgkmcnt ordering suffices (no barrier)
        bfr8 pf[2];
        pf[0] = *(const bfr8*)&Ps[w][g2][r15][0];
        pf[1] = *(const bfr8*)&Ps[w][4 + g2][r15][0];

        // ---- O' += V^T @ P ----
        #pragma unroll
        for (int ch = 0; ch < 4; ++ch) {
            const int d = ch * 16 + r15;
            const bfr8 vf0 = *(const bfr8*)&Vs[buf][d][(g2 ^ (r15 & 7)) * 8];
            const bfr8 vf1 = *(const bfr8*)&Vs[buf][d][((4 + g2) ^ (r15 & 7)) * 8];
            o[ch] = __builtin_amdgcn_mfma_f32_16x16x32_bf16(vf0, pf[0], o[ch], 0, 0, 0);
            o[ch] = __builtin_amdgcn_mfma_f32_16x16x32_bf16(vf1, pf[1], o[ch], 0, 0, 0);
        }
    }

    const float inv = 1.f / rden;
    const int b = bh >> 4, h = bh & 15;
    unsigned short* Ob = O + ((size_t)b * SEQ + q) * DMODEL + h * HDIM + g2 * 4;
    #pragma unroll
    for (int ch = 0; ch < 4; ++ch) {
        uint2 pk;
        pk.x = pack2bf(o[ch][0] * inv, o[ch][1] * inv);
        pk.y = pack2bf(o[ch][2] * inv, o[ch][3] * inv);
        *(uint2*)(Ob + ch * 16) = pk;
    }
}

// ---------------- launch ----------------
extern "C" void kernel_launch(void* const* d_in, const int* in_sizes, int n_in,
                              void* d_out, int out_size, void* d_ws, size_t ws_size,
                              hipStream_t stream) {
    const float* x   = (const float*)d_in[0];
    const float* w_q = (const float*)d_in[1];
    const float* b_q = (const float*)d_in[2];
    const float* w_k = (const float*)d_in[3];
    const float* b_k = (const float*)d_in[4];
    const float* w_v = (const float*)d_in[5];
    const float* b_v = (const float*)d_in[6];
    const float* w_o = (const float*)d_in[7];
    const float* b_o = (const float*)d_in[8];
    float* out = (float*)d_out;

    const size_t NX = (size_t)MROWS * DMODEL;   // 4,194,304
    const size_t NW = (size_t)DMODEL * DMODEL;  // 1,048,576 = 2^20
    unsigned short* xb    = (unsigned short*)d_ws;
    unsigned short* wcomb = xb + NX;            // [3072][1024] = wq|wk|wv, then wo
    unsigned short* wob   = wcomb + 3 * NW;
    unsigned short* Qw    = wob + NW;           // [B,H,T,64] (scaled)
    unsigned short* Kw    = Qw + NX;            // [B,H,T,64]
    unsigned short* VTw   = Kw + NX;            // [B,H,64,T]
    unsigned short* Ow    = VTw + NX;           // [B,T,1024]

    cast_bf16<<<1024, 256, 0, stream>>>(x, xb, (int)NX);
    cast4_bf16<<<2048, 256, 0, stream>>>(w_q, w_k, w_v, w_o, wcomb);

    // fused QKV projection: [4096,1024] @ [3072,1024]^T
    gemm_bf16<128, 0><<<dim3(24, 32), 256, 0, stream>>>(xb, wcomb, b_q, b_k, b_v, Qw);

    attn_mfma<<<dim3(32, 32), 256, 0, stream>>>(Qw, Kw, VTw, Ow);

    // output projection: [4096,1024] @ [1024,1024]^T -> fp32
    gemm_bf16<64, 2><<<dim3(8, 64), 256, 0, stream>>>(Ow, wob, b_o, nullptr, nullptr, out);
}

// Round 8
// 161.201 us; speedup vs baseline: 1.1618x; 1.1618x over previous
//
#include <hip/hip_runtime.h>
#include <hip/hip_bf16.h>
#include <math.h>

#define BATCH 2
#define SEQ   2048
#define DMODEL 1024
#define NHEADS 16
#define HDIM  64
#define MROWS (BATCH*SEQ)   // 4096
#define QSCALE 0.1803368801111204f   // 0.125 * log2(e); attention uses exp2

typedef __attribute__((ext_vector_type(8))) short bfr8;   // 8 bf16 (4 VGPRs)
typedef __attribute__((ext_vector_type(4))) float f32x4;  // MFMA C/D

__device__ inline unsigned short f2bf(float f) {
    union { float f; unsigned u; } v; v.f = f;
    unsigned r = v.u + 0x7FFFu + ((v.u >> 16) & 1u);   // RNE
    return (unsigned short)(r >> 16);
}

__device__ inline unsigned pack2bf(float a, float b) {   // low=a, high=b
    union { __hip_bfloat162 h; unsigned u; } cv;
    cv.h = __float22bfloat162_rn(float2{a, b});
    return cv.u;
}

__device__ inline void gload16(const unsigned short* g, unsigned short* l) {
    __builtin_amdgcn_global_load_lds((const __attribute__((address_space(1))) void*)g,
        (__attribute__((address_space(3))) void*)l, 16, 0, 0);
}

// ---------------- casts fp32 -> bf16 ----------------
__global__ __launch_bounds__(256) void cast_bf16(const float* __restrict__ in,
                                                 unsigned short* __restrict__ out, int n) {
    int i = (blockIdx.x * 256 + threadIdx.x) * 4;
    const int stride = gridDim.x * 256 * 4;
    for (; i < n; i += stride) {
        float4 v = *(const float4*)(in + i);
        ushort4 o;
        o.x = f2bf(v.x); o.y = f2bf(v.y); o.z = f2bf(v.z); o.w = f2bf(v.w);
        *(ushort4*)(out + i) = o;
    }
}

// 4 weight matrices (each 2^20 elems) -> contiguous dst
__global__ __launch_bounds__(256) void cast4_bf16(
    const float* __restrict__ a, const float* __restrict__ b,
    const float* __restrict__ c, const float* __restrict__ d,
    unsigned short* __restrict__ out) {
    const int NW = 1 << 20;
    int i = (blockIdx.x * 256 + threadIdx.x) * 4;
    const int stride = gridDim.x * 256 * 4;
    for (; i < 4 * NW; i += stride) {
        const int seg = i >> 20;
        const float* src = seg == 0 ? a : seg == 1 ? b : seg == 2 ? c : d;
        float4 v = *(const float4*)(src + (i & (NW - 1)));
        ushort4 o;
        o.x = f2bf(v.x); o.y = f2bf(v.y); o.z = f2bf(v.z); o.w = f2bf(v.w);
        *(ushort4*)(out + i) = o;
    }
}

// ---------------- bf16 MFMA GEMM: Y = A @ W^T + bias ----------------
// Tile BM x 128, BK=32, 4 waves. 3-buffer LDS pipeline, 2-deep prefetch,
// counted vmcnt (never 0 in steady state) fused with s_barrier.  [R7, kept]
// MODE 0: N=3072 fused QKV; proj=col/1024; Q scaled by QSCALE; Q,K->[B,H,T,64], V->[B,H,64,T]
// MODE 2: N=1024, fp32 linear output [4096,1024], bias b0
template<int BM, int MODE>
__global__ __launch_bounds__(256) void gemm_bf16(
    const unsigned short* __restrict__ A, const unsigned short* __restrict__ W,
    const float* __restrict__ b0, const float* __restrict__ b1,
    const float* __restrict__ b2, void* __restrict__ Y)
{
    __shared__ __align__(16) unsigned short As[3][4][BM][8];
    __shared__ __align__(16) unsigned short Bs[3][4][128][8];

    constexpr int NT  = 32;            // K / 32
    constexpr int NLD = BM / 64 + 2;   // gload_lds instrs per thread per stage

    const int tid = threadIdx.x;
    const int l = tid & 63, w = tid >> 6;
    const int wr = w >> 1, wc = w & 1;
    const int m0 = blockIdx.y * BM, n0 = blockIdx.x * 128;
    const int r15 = l & 15, g = l >> 4;
    constexpr int MR = BM / 32;

    f32x4 acc[MR][4] = {};

    auto stage = [&](int buf, int t) {
        const int k0 = t * 32;
        #pragma unroll
        for (int s = 0; s < BM / 64; ++s) {
            int idx = s * 256 + tid;
            int row = idx % BM, kg = idx / BM;
            gload16(A + (size_t)(m0 + row) * 1024 + k0 + kg * 8, &As[buf][kg][row][0]);
        }
        #pragma unroll
        for (int s = 0; s < 2; ++s) {
            int idx = s * 256 + tid;
            int row = idx & 127, kg = idx >> 7;
            gload16(W + (size_t)(n0 + row) * 1024 + k0 + kg * 8, &Bs[buf][kg][row][0]);
        }
    };

    stage(0, 0);
    stage(1, 1);

    for (int t = 0; t < NT; ++t) {
        // tile t landed (newest stage may remain in flight), then block-wide sync
        if (t < NT - 1)
            asm volatile("s_waitcnt vmcnt(%0)\ns_barrier" :: "n"(NLD) : "memory");
        else
            asm volatile("s_waitcnt vmcnt(0)\ns_barrier" ::: "memory");
        if (t + 2 < NT) stage((t + 2) % 3, t + 2);

        const int buf = t % 3;
        bfr8 a[MR], b[4];
        #pragma unroll
        for (int m = 0; m < MR; ++m)
            a[m] = *(const bfr8*)&As[buf][g][wr * (BM / 2) + m * 16 + r15][0];
        #pragma unroll
        for (int n = 0; n < 4; ++n)
            b[n] = *(const bfr8*)&Bs[buf][g][wc * 64 + n * 16 + r15][0];
        #pragma unroll
        for (int m = 0; m < MR; ++m)
            #pragma unroll
            for (int n = 0; n < 4; ++n)
                acc[m][n] = __builtin_amdgcn_mfma_f32_16x16x32_bf16(a[m], b[n], acc[m][n], 0, 0, 0);
    }

    const size_t NX = (size_t)MROWS * DMODEL;
    #pragma unroll
    for (int m = 0; m < MR; ++m) {
        const int rowb = m0 + wr * (BM / 2) + m * 16 + g * 4;
        #pragma unroll
        for (int n = 0; n < 4; ++n) {
            const int col = n0 + wc * 64 + n * 16 + r15;
            const int proj = col >> 10, within = col & 1023;
            const float bc = (MODE == 2) ? b0[col]
                           : (proj == 0 ? b0[within] : proj == 1 ? b1[within] : b2[within]);
            #pragma unroll
            for (int i = 0; i < 4; ++i) {
                float v = acc[m][n][i] + bc;
                const int rr = rowb + i;
                if (MODE == 2) {
                    ((float*)Y)[(size_t)rr * 1024 + col] = v;
                } else {
                    if (proj == 0) v *= QSCALE;
                    const int bb = rr >> 11, tt = rr & 2047;
                    const int hh = within >> 6, dd = within & 63;
                    unsigned short* dst = (unsigned short*)Y + (size_t)proj * NX;
                    size_t idx;
                    if (proj < 2)
                        idx = (((size_t)bb * NHEADS + hh) * SEQ + tt) * HDIM + dd;
                    else
                        idx = (((size_t)bb * NHEADS + hh) * HDIM + dd) * SEQ + tt;
                    dst[idx] = f2bf(v);
                }
            }
        }
    }
}

// ---------------- MFMA flash attention (causal, fully lane-local softmax) ----------------
// [reverted to R6 structure: 2-buffer, 40KB LDS, 4 blocks/CU, __syncthreads drain —
//  measured ~35µs vs R7 3-buffer's 87µs (occupancy loss dominated)]
// Q,K: [B,H,T,64] bf16 (Q pre-scaled by 0.125*log2e); VT: [B,H,64,T]; O: [B,T,1024] bf16.
// Block: 4 waves x 16 q-rows = 64 q. S^T = mfma(K, Q^T): C col = q = r15.
// PV transposed: o' = mfma(V^T-frag, P-frag). Softmax fully lane-local; defer-max THR=8.
__global__ __launch_bounds__(256, 4) void attn_mfma(
    const unsigned short* __restrict__ Q, const unsigned short* __restrict__ K,
    const unsigned short* __restrict__ VT, unsigned short* __restrict__ O)
{
    __shared__ __align__(16) unsigned short Ks[2][64][64];   // [kv][d] granule-swizzled (16K)
    __shared__ __align__(16) unsigned short Vs[2][64][64];   // [d][kv] granule-swizzled (16K)
    __shared__ __align__(16) unsigned short Ps[4][8][16][8]; // [wave][kg][q][e]  (8K)

    const int tid = threadIdx.x;
    const int l = tid & 63, w = tid >> 6;
    const int r15 = l & 15, g2 = l >> 4;          // g2 = 0..3
    const int qt = (blockIdx.x + blockIdx.y) & 31;   // decorrelate length from CU
    const int q0 = SEQ - 64 - qt * 64;
    const int q  = q0 + w * 16 + r15;             // this lane's q column
    const int bh = blockIdx.y;

    const unsigned short* Qb = Q + (size_t)bh * SEQ * HDIM;
    const unsigned short* Kb = K + (size_t)bh * SEQ * HDIM;
    const unsigned short* Vb = VT + (size_t)bh * HDIM * SEQ;

    // Q B-frag: lane holds Q[q][ks*32 + g2*8 .. +7]
    bfr8 qf[2];
    qf[0] = *(const bfr8*)(Qb + (size_t)q * HDIM + g2 * 8);
    qf[1] = *(const bfr8*)(Qb + (size_t)q * HDIM + 32 + g2 * 8);

    auto stage = [&](int buf, int kv0) {
        #pragma unroll
        for (int s = 0; s < 2; ++s) {
            int idx = s * 256 + tid;               // 512 granules each of K, V
            int row = idx >> 3, gs = idx & 7;
            gload16(Kb + (size_t)(kv0 + row) * HDIM + ((gs ^ (row & 7)) * 8), &Ks[buf][row][gs * 8]);
            gload16(Vb + (size_t)row * SEQ + kv0 + ((gs ^ (row & 7)) * 8), &Vs[buf][row][gs * 8]);
        }
    };

    f32x4 o[4] = {};                 // o[ch][i]: d = ch*16 + g2*4 + i, col q
    float m = -INFINITY, rden = 0.f;

    const int ntiles = q0 / 64 + 1;
    stage(0, 0);
    __syncthreads();

    for (int kt = 0; kt < ntiles; ++kt) {
        const int kv0 = kt * 64, buf = kt & 1;
        if (kt + 1 < ntiles) stage(buf ^ 1, kv0 + 64);

        // ---- S^T = K @ Q^T : s[c][i], kv = c*16 + g2*4 + i, q = col r15 ----
        f32x4 s[4];
        #pragma unroll
        for (int c = 0; c < 4; ++c) {
            const int rk = c * 16 + r15;
            const bfr8 kf0 = *(const bfr8*)&Ks[buf][rk][(g2 ^ (r15 & 7)) * 8];
            const bfr8 kf1 = *(const bfr8*)&Ks[buf][rk][((4 + g2) ^ (r15 & 7)) * 8];
            f32x4 z = {0.f, 0.f, 0.f, 0.f};
            z = __builtin_amdgcn_mfma_f32_16x16x32_bf16(kf0, qf[0], z, 0, 0, 0);
            s[c] = __builtin_amdgcn_mfma_f32_16x16x32_bf16(kf1, qf[1], z, 0, 0, 0);
        }

        if (kt == ntiles - 1) {      // causal mask: only the diagonal tile
            #pragma unroll
            for (int c = 0; c < 4; ++c)
                #pragma unroll
                for (int i = 0; i < 4; ++i)
                    if (kv0 + c * 16 + g2 * 4 + i > q) s[c][i] = -INFINITY;
        }

        // ---- lane-local online softmax with defer-max ----
        float tm = s[0][0];
        #pragma unroll
        for (int c = 0; c < 4; ++c)
            #pragma unroll
            for (int i = 0; i < 4; ++i) tm = fmaxf(tm, s[c][i]);
        tm = fmaxf(tm, __shfl_xor(tm, 16));
        tm = fmaxf(tm, __shfl_xor(tm, 32));
        if (__any(tm > m + 8.f)) {            // rescale (always taken on first tile)
            const float mn = fmaxf(m, tm);
            const float scl = exp2f(m - mn);  // 0 on first tile
            m = mn;
            rden *= scl;
            #pragma unroll
            for (int ch = 0; ch < 4; ++ch)
                #pragma unroll
                for (int i = 0; i < 4; ++i) o[ch][i] *= scl;
        }
        float ls = 0.f;
        #pragma unroll
        for (int c = 0; c < 4; ++c)
            #pragma unroll
            for (int i = 0; i < 4; ++i) {
                const float p = exp2f(s[c][i] - m);
                s[c][i] = p;
                ls += p;
            }
        ls += __shfl_xor(ls, 16);
        ls += __shfl_xor(ls, 32);
        rden += ls;

        // ---- P -> LDS in B-frag layout: Ps[kg][q][e] = P[kv=kg*8+e][q] ----
        {
            const int eb = (g2 & 1) * 4;
            #pragma unroll
            for (int c = 0; c < 4; ++c) {
                const int kg = c * 2 + (g2 >> 1);
                *(unsigned*)&Ps[w][kg][r15][eb]     = pack2bf(s[c][0], s[c][1]);
                *(unsigned*)&Ps[w][kg][r15][eb + 2] = pack2bf(s[c][2], s[c][3]);
            }
        }
        // wave-private buffer: within-wave lgkmcnt ordering suffices (no barrier)
        bfr8 pf[2];
        pf[0] = *(const bfr8*)&Ps[w][g2][r15][0];
        pf[1] = *(const bfr8*)&Ps[w][4 + g2][r15][0];

        // ---- O' += V^T @ P ----
        #pragma unroll
        for (int ch = 0; ch < 4; ++ch) {
            const int d = ch * 16 + r15;
            const bfr8 vf0 = *(const bfr8*)&Vs[buf][d][(g2 ^ (r15 & 7)) * 8];
            const bfr8 vf1 = *(const bfr8*)&Vs[buf][d][((4 + g2) ^ (r15 & 7)) * 8];
            o[ch] = __builtin_amdgcn_mfma_f32_16x16x32_bf16(vf0, pf[0], o[ch], 0, 0, 0);
            o[ch] = __builtin_amdgcn_mfma_f32_16x16x32_bf16(vf1, pf[1], o[ch], 0, 0, 0);
        }
        __syncthreads();   // protect K/V buffers (also drains staged loads)
    }

    const float inv = 1.f / rden;
    const int b = bh >> 4, h = bh & 15;
    unsigned short* Ob = O + ((size_t)b * SEQ + q) * DMODEL + h * HDIM + g2 * 4;
    #pragma unroll
    for (int ch = 0; ch < 4; ++ch) {
        uint2 pk;
        pk.x = pack2bf(o[ch][0] * inv, o[ch][1] * inv);
        pk.y = pack2bf(o[ch][2] * inv, o[ch][3] * inv);
        *(uint2*)(Ob + ch * 16) = pk;
    }
}

// ---------------- launch ----------------
extern "C" void kernel_launch(void* const* d_in, const int* in_sizes, int n_in,
                              void* d_out, int out_size, void* d_ws, size_t ws_size,
                              hipStream_t stream) {
    const float* x   = (const float*)d_in[0];
    const float* w_q = (const float*)d_in[1];
    const float* b_q = (const float*)d_in[2];
    const float* w_k = (const float*)d_in[3];
    const float* b_k = (const float*)d_in[4];
    const float* w_v = (const float*)d_in[5];
    const float* b_v = (const float*)d_in[6];
    const float* w_o = (const float*)d_in[7];
    const float* b_o = (const float*)d_in[8];
    float* out = (float*)d_out;

    const size_t NX = (size_t)MROWS * DMODEL;   // 4,194,304
    const size_t NW = (size_t)DMODEL * DMODEL;  // 1,048,576 = 2^20
    unsigned short* xb    = (unsigned short*)d_ws;
    unsigned short* wcomb = xb + NX;            // [3072][1024] = wq|wk|wv, then wo
    unsigned short* wob   = wcomb + 3 * NW;
    unsigned short* Qw    = wob + NW;           // [B,H,T,64] (scaled)
    unsigned short* Kw    = Qw + NX;            // [B,H,T,64]
    unsigned short* VTw   = Kw + NX;            // [B,H,64,T]
    unsigned short* Ow    = VTw + NX;           // [B,T,1024]

    cast_bf16<<<1024, 256, 0, stream>>>(x, xb, (int)NX);
    cast4_bf16<<<2048, 256, 0, stream>>>(w_q, w_k, w_v, w_o, wcomb);

    // fused QKV projection: [4096,1024] @ [3072,1024]^T
    gemm_bf16<128, 0><<<dim3(24, 32), 256, 0, stream>>>(xb, wcomb, b_q, b_k, b_v, Qw);

    attn_mfma<<<dim3(32, 32), 256, 0, stream>>>(Qw, Kw, VTw, Ow);

    // output projection: [4096,1024] @ [1024,1024]^T -> fp32
    gemm_bf16<64, 2><<<dim3(8, 64), 256, 0, stream>>>(Ow, wob, b_o, nullptr, nullptr, out);
}